// Round 6
// baseline (514.026 us; speedup 1.0000x reference)
//
#include <hip/hip_runtime.h>
#include <hip/hip_bf16.h>

typedef float f32x4 __attribute__((ext_vector_type(4)));
typedef int   i32x4 __attribute__((ext_vector_type(4)));

#define DELTA 5e-5f
#define LIST_CAP 4194304

// ---------------- weight prep: fold BN, per-cout i8 digit decomposition -------
// S = max_k |w*inv| / 127 (rounded to f32). d0=rint(w/S); d1=rint(254r/S);
// d2=rint(64516 r/S) (conv1 only). Layout per conv per split: [kc][cout][kk],
// k=r*128+cin, kc=k>>6, kk=k&63; split stride 147456 B; conv2 at +442368.
// Also zeroes the 2KB zero-buffer used by global_load_lds OOB lanes.
__global__ void prep_kernel(const float* __restrict__ w1, const float* __restrict__ g1,
                            const float* __restrict__ b1, const float* __restrict__ m1,
                            const float* __restrict__ v1,
                            const float* __restrict__ w2, const float* __restrict__ g2,
                            const float* __restrict__ b2, const float* __restrict__ m2,
                            const float* __restrict__ v2,
                            signed char* __restrict__ wp, float* __restrict__ off,
                            float* __restrict__ scl, int* __restrict__ cnt,
                            signed char* __restrict__ zb)
{
    __shared__ double red[128];
    const int blk  = blockIdx.x;       // 256 blocks = conv*128 + cout
    const int conv = blk >> 7;
    const int cout = blk & 127;
    const int cin  = threadIdx.x;      // 128 threads
    const float* w  = conv ? w2 : w1;
    const float* g  = conv ? g2 : g1;
    const float* bb = conv ? b2 : b1;
    const float* mm = conv ? m2 : m1;
    const float* vr = conv ? v2 : v1;
    if (blk == 0) { int4 z = {0,0,0,0}; *(int4*)(zb + cin * 16) = z; }  // 2KB zeros
    const float invf = g[cout] / sqrtf(vr[cout] + 1e-5f);
    double wv[9];
    double mx = 0.0;
#pragma unroll
    for (int r = 0; r < 9; ++r) {
        wv[r] = (double)w[(size_t)(cout * 128 + cin) * 9 + r] * (double)invf;
        mx = fmax(mx, fabs(wv[r]));
    }
    red[cin] = mx;
    __syncthreads();
    for (int s = 64; s > 0; s >>= 1) {
        if (cin < s) red[cin] = fmax(red[cin], red[cin + s]);
        __syncthreads();
    }
    double S = red[0];
    S = (S > 0.0) ? (double)(float)(S / 127.0) : 1.0;
    const size_t base = conv ? (size_t)442368 : (size_t)0;
#pragma unroll
    for (int r = 0; r < 9; ++r) {
        double x = wv[r];
        const int k = r * 128 + cin;
        const size_t pos = ((size_t)(k >> 6) * 128 + cout) * 64 + (k & 63);
        int d0 = (int)rint(x / S);          x -= (double)d0 * S;
        int d1 = (int)rint(x * 254.0 / S);  x -= (double)d1 * S / 254.0;
        wp[base + pos]          = (signed char)d0;
        wp[base + 147456 + pos] = (signed char)d1;
        if (conv == 0) {
            int d2 = (int)rint(x * 64516.0 / S);
            wp[base + 294912 + pos] = (signed char)d2;
        }
    }
    if (cin == 0) {
        scl[conv * 128 + cout] = (float)S;
        off[conv * 128 + cout] = bb[cout] - mm[cout] * invf;
        if (blk == 0) cnt[0] = 0;          // ws re-poisoned every launch
    }
}

// ---------------- IF neuron #1: x [T,B,C,H,W] f32 -> spikes NHWC i8 -----------
// fp64 membrane: bit-matches an fp64 reference's spike decisions.
__global__ void if1_kernel(const float* __restrict__ x, signed char* __restrict__ s1)
{
    const int blk = blockIdx.x;        // 1024 = B*H
    const int b   = blk >> 5;
    const int h   = blk & 31;
    const int tid = threadIdx.x;
    const int w   = tid & 31;
    const int g   = tid >> 5;          // 8 groups of 16 channels
    double v[16];
#pragma unroll
    for (int i = 0; i < 16; ++i) v[i] = 0.0;
    for (int t = 0; t < 8; ++t) {
        const size_t xbase = ((((size_t)t * 32 + b) * 128 + g * 16) * 32 + h) * 32 + w;
        unsigned wds[4] = {0u, 0u, 0u, 0u};
#pragma unroll
        for (int i = 0; i < 16; ++i) {
            v[i] += (double)x[xbase + (size_t)i * 1024];
            const bool s = (v[i] >= 1.0);
            if (s) { wds[i >> 2] |= 1u << (8 * (i & 3)); v[i] = 0.0; }
        }
        int4 pk; pk.x = wds[0]; pk.y = wds[1]; pk.z = wds[2]; pk.w = wds[3];
        *(int4*)(s1 + (((size_t)(t * 32 + b) * 1024 + h * 32 + w) * 128 + g * 16)) = pk;
    }
}

// ---------------- conv1 (+folded BN) fused with IF#2, fat-tile ----------------
// Block = (cgrp, b, 8-row strip): grid 512, 1 block/CU (155.6 KB LDS). Weights
// (32 couts x 3 splits, 110.6 KB) staged to LDS once. 4 waves, each 2 rows
// (64 px) x 32 couts: per kc 4 af + 6 wb ds_read_b128 feed 24 MFMA
// (0.42 reads/MFMA vs round-5's 0.83 -> LDS-read pipe no longer the ceiling).
// acc 96 AGPR + v 32; at 1 wave/SIMD the ~512-reg budget absorbs it (no spill).
// img single-buffered; stage(t+1) issued right after the read-done barrier so
// the membrane epilogue hides the load latency. Membrane v persists across t;
// DELTA-flagged sites get exact fp64 redo (digit error ~1e-7 << DELTA).
__global__ __launch_bounds__(256, 1)
void conv1_if2_kernel(const signed char* __restrict__ sin,
                      const signed char* __restrict__ wp,
                      const float* __restrict__ off, const float* __restrict__ scl,
                      const signed char* __restrict__ zb,
                      signed char* __restrict__ s2q,
                      int* __restrict__ cnt, int* __restrict__ list)
{
    __shared__ signed char lds_all[110592 + 45056];   // 155,648 B -> 1 block/CU
    signed char* wlds = lds_all;
    signed char* img  = lds_all + 110592;             // 10 rows x 34 x 128 (+pad)
    const int tid  = threadIdx.x;
    const int blk  = blockIdx.x;       // 512 = cgrp*128 + b*4 + st8
    const int cgrp = blk >> 7;         // twins at stride 128 (%8==0): same XCD
    const int b    = (blk >> 2) & 31;
    const int st8  = blk & 3;
    const int wv   = tid >> 6;         // wave -> rows y0+2wv, y0+2wv+1
    const int lane15 = tid & 15;
    const int q    = (tid >> 4) & 3;
    const int y0   = st8 << 3;

    // ---- stage weights: 6912 x 16B units = 27/thread, linear LDS dest --------
#pragma unroll
    for (int k = 0; k < 27; ++k) {
        const int u   = tid + k * 256;
        const int sk  = u >> 7;              // (split*18+kc)
        const int a   = (u & 127) * 16;
        const int asw = a ^ (((a >> 7) & 3) << 4);   // involution on bits 4-5
        const signed char* src = wp + sk * 8192 + cgrp * 2048 + asw;
        __builtin_amdgcn_global_load_lds(
            (const __attribute__((address_space(1))) unsigned int*)src,
            (__attribute__((address_space(3))) unsigned int*)(wlds + u * 16), 16, 0, 0);
    }

    // img staging offsets (t-invariant): 2720 real units (10 rows x 34 x 8), 96 pad
    int soff[11];
#pragma unroll
    for (int k = 0; k < 11; ++k) {
        const int unit = tid + k * 256;
        const int sp = unit >> 3, G = unit & 7;
        const int row = sp / 34, col = sp - row * 34;
        const int y = y0 + row - 1, xg = col - 1;
        soff[k] = (unit < 2720 && y >= 0 && y < 32 && xg >= 0 && xg < 32)
                  ? ((y * 32 + xg) * 128 + ((G ^ (col & 7)) * 16)) : -1;
    }

    float offv[2], svf[2];
    int aw[2];
#pragma unroll
    for (int j = 0; j < 2; ++j) {
        const int c = cgrp * 32 + j * 16 + lane15;
        offv[j] = off[c];
        svf[j]  = scl[c];
        int a = (j * 16 + lane15) * 64 + q * 16;
        aw[j] = a ^ (((a >> 7) & 3) << 4);
    }

#define STAGE1(tsel)                                                              \
    {                                                                             \
        const signed char* gbase = sin + (size_t)((tsel) * 32 + b) * 131072;      \
        _Pragma("unroll")                                                         \
        for (int k = 0; k < 11; ++k) {                                            \
            const signed char* src = (soff[k] >= 0) ? (gbase + soff[k])           \
                                                    : (zb + (tid & 63) * 16);     \
            __builtin_amdgcn_global_load_lds(                                     \
                (const __attribute__((address_space(1))) unsigned int*)src,       \
                (__attribute__((address_space(3))) unsigned int*)                 \
                    (img + (tid + k * 256) * 16), 16, 0, 0);                      \
        }                                                                         \
    }

    STAGE1(0);

    float v[4][2][4];
#pragma unroll
    for (int i = 0; i < 4; ++i)
#pragma unroll
        for (int j = 0; j < 2; ++j)
#pragma unroll
            for (int rg = 0; rg < 4; ++rg) v[i][j][rg] = 0.f;
    unsigned fmask = 0;

    __syncthreads();   // drains weights + img[0]

    for (int t = 0; t < 8; ++t) {
        i32x4 acc[4][2][3];
#pragma unroll
        for (int i = 0; i < 4; ++i)
#pragma unroll
            for (int j = 0; j < 2; ++j)
#pragma unroll
                for (int s = 0; s < 3; ++s)
#pragma unroll
                    for (int rg = 0; rg < 4; ++rg) acc[i][j][s][rg] = 0;

#pragma unroll
        for (int tap = 0; tap < 9; ++tap) {
            const int dy = tap / 3 - 1;
            const int dx = tap - (tap / 3) * 3 - 1;
#pragma unroll
            for (int ci = 0; ci < 2; ++ci) {
                const int kc = tap * 2 + ci;
                i32x4 af[4];
#pragma unroll
                for (int i4 = 0; i4 < 4; ++i4) {
                    const int rowl = wv * 2 + (i4 >> 1) + 1 + dy;      // 0..9
                    const int col  = (i4 & 1) * 16 + lane15 + 1 + dx;  // 0..33
                    const int g    = (ci * 4 + q) ^ (col & 7);
                    af[i4] = *(const i32x4*)&img[(rowl * 34 + col) * 128 + g * 16];
                }
#pragma unroll
                for (int s = 0; s < 3; ++s)
#pragma unroll
                    for (int j = 0; j < 2; ++j) {
                        const i32x4 wb = *(const i32x4*)&wlds[(s * 18 + kc) * 2048 + aw[j]];
#pragma unroll
                        for (int i4 = 0; i4 < 4; ++i4)
                            acc[i4][j][s] = __builtin_amdgcn_mfma_i32_16x16x64_i8(
                                af[i4], wb, acc[i4][j][s], 0, 0, 0);
                    }
            }
        }

        __syncthreads();               // all waves done reading img[t]
        if (t < 7) STAGE1(t + 1);      // async loads; epilogue hides latency

        // membrane + spike + flag; pack 4 consecutive pixels into one u32.
        // C/D map: col=lane&15 (cout), row=q*4+rg (pixel within 16-px group).
        const size_t g4t = (size_t)(t * 32 + b) * 256;
#pragma unroll
        for (int i4 = 0; i4 < 4; ++i4) {
            const int g4r = (y0 + wv * 2 + (i4 >> 1)) * 8 + (i4 & 1) * 4 + q;
#pragma unroll
            for (int j = 0; j < 2; ++j) {
                unsigned pk = 0;
#pragma unroll
                for (int rg = 0; rg < 4; ++rg) {
                    const float yv = fmaf((float)acc[i4][j][0][rg]
                                   + (float)acc[i4][j][1][rg] * (1.0f / 254.0f)
                                   + (float)acc[i4][j][2][rg] * (1.0f / 64516.0f),
                                   svf[j], offv[j]);
                    v[i4][j][rg] += yv;
                    const float d = v[i4][j][rg] - 1.0f;
                    if (fabsf(d) < DELTA) fmask |= 1u << (i4 * 8 + j * 4 + rg);
                    if (d >= 0.0f) { pk |= 1u << (8 * rg); v[i4][j][rg] = 0.f; }
                }
                *(unsigned*)(s2q + ((g4t + g4r) * 128 + cgrp * 32 + j * 16 + lane15) * 4) = pk;
            }
        }

        if (t < 7) __syncthreads();    // drain staging -> img[t+1] ready
    }
#undef STAGE1

    if (fmask) {
#pragma unroll 1
        for (int k = 0; k < 32; ++k)
            if ((fmask >> k) & 1) {
                const int i4 = k >> 3, j = (k >> 2) & 1, rg = k & 3;
                const int p = (y0 + wv * 2 + (i4 >> 1)) * 32 + (i4 & 1) * 16 + q * 4 + rg;
                const int c = cgrp * 32 + j * 16 + lane15;
                const int pos = atomicAdd(cnt, 1);
                if (pos < LIST_CAP)
                    list[pos] = (b << 17) | (p << 7) | c;
            }
    }
}

// ---------------- IF#2 phase B: fp64 redo from stored s1 spikes ---------------
__global__ __launch_bounds__(256)
void redo_kernel(const signed char* __restrict__ s1, const float* __restrict__ w1,
                 const float* __restrict__ g1, const float* __restrict__ b1,
                 const float* __restrict__ m1, const float* __restrict__ v1r,
                 const int* __restrict__ cnt, const int* __restrict__ list,
                 signed char* __restrict__ s2q)
{
    __shared__ double red[256][8];   // 16 KB
    const int count = min(cnt[0], LIST_CAP);
    const int tid = threadIdx.x;
    const int cin = tid & 127;
    const int tg  = tid >> 7;
    for (int i = blockIdx.x; i < count; i += gridDim.x) {
        const int pk = list[i];
        const int b = pk >> 17, p = (pk >> 7) & 1023, c = pk & 127;
        const int h = p >> 5, w_ = p & 31;
        double part[8];
#pragma unroll
        for (int t = 0; t < 8; ++t) part[t] = 0.0;
        const int tap0 = tg ? 5 : 0, tap1 = tg ? 9 : 5;
        for (int tap = tap0; tap < tap1; ++tap) {
            const int hh = h + tap / 3 - 1;
            const int ww = w_ + tap - (tap / 3) * 3 - 1;
            if (hh < 0 || hh > 31 || ww < 0 || ww > 31) continue;
            const int pix = hh * 32 + ww;
            const double wv = (double)w1[(size_t)(c * 128 + cin) * 9 + tap];
#pragma unroll
            for (int t = 0; t < 8; ++t)
                if (s1[((size_t)(t * 32 + b) * 1024 + pix) * 128 + cin]) part[t] += wv;
        }
#pragma unroll
        for (int t = 0; t < 8; ++t) red[tid][t] = part[t];
        __syncthreads();
        for (int s = 128; s > 0; s >>= 1) {
            if (tid < s)
#pragma unroll
                for (int t = 0; t < 8; ++t) red[tid][t] += red[tid + s][t];
            __syncthreads();
        }
        if (tid == 0) {
            const double inv  = (double)g1[c] / sqrt((double)v1r[c] + 1e-5);
            const double offc = (double)b1[c] - (double)m1[c] * inv;
            double v = 0.0;
#pragma unroll
            for (int t = 0; t < 8; ++t) {
                v += red[0][t] * inv + offc;
                const bool s = (v >= 1.0);
                s2q[(((size_t)(t * 32 + b) * 256 + (p >> 2)) * 128 + c) * 4 + (p & 3)]
                    = s ? 1 : 0;
                if (s) v = 0.0;
            }
        }
        __syncthreads();   // LDS reused next site
    }
}

// ---------------- conv2 (+folded BN), LDS weights + t-loop, NCHW out ----------
// Block = (cgrp, b, 16-row strip): grid 256 = 1 block/CU. Weights (32 couts x
// 2 splits, 73.7 KB) LDS-resident; img = 18 rows x 34 x 128 (78.3 KB). t-loop
// inside re-uses weights 8x (kills the 590 MB L2 weight ring + its latency
// stalls). 4 waves x (128 px x 32 couts): per kc 8 af + 4 wb reads feed
// 32 MFMA (0.375 reads/MFMA -> MFMA-bound). Staging transposes pixel-quad s2q
// into pixel-major LDS via v_perm (round-5-verified path).
__global__ __launch_bounds__(256, 1)
void conv2_kernel(const signed char* __restrict__ s2q, const signed char* __restrict__ wp,
                  const float* __restrict__ off, const float* __restrict__ scl,
                  float* __restrict__ out)
{
    __shared__ signed char lds_all[73728 + 78336];   // 152,064 B
    signed char* wlds = lds_all;
    signed char* img  = lds_all + 73728;
    const int tid  = threadIdx.x;
    const int blk  = blockIdx.x;          // 256 = cgrp*64 + b*2 + st16
    const int cgrp = blk >> 6;            // twins at stride 64 (%8==0): same XCD
    const int b    = (blk >> 1) & 31;
    const int st16 = blk & 1;
    const int wv   = tid >> 6;            // wave -> 4 rows
    const int lane15 = tid & 15;
    const int q    = (tid >> 4) & 3;
    const int y0   = st16 << 4;

    // ---- stage weights: 4608 x 16B units = 18/thread ----
#pragma unroll
    for (int k = 0; k < 18; ++k) {
        const int u   = tid + k * 256;
        const int sk  = u >> 7;
        const int a   = (u & 127) * 16;
        const int asw = a ^ (((a >> 7) & 3) << 4);
        const signed char* src = wp + sk * 8192 + cgrp * 2048 + asw;
        __builtin_amdgcn_global_load_lds(
            (const __attribute__((address_space(1))) unsigned int*)src,
            (__attribute__((address_space(3))) unsigned int*)(wlds + u * 16), 16, 0, 0);
    }

    // halo columns (col 0, 33) zero once: 18 rows x 2 sides x 8 G = 288 units
#pragma unroll
    for (int pass = 0; pass < 2; ++pass) {
        const int u = tid + pass * 256;
        if (u < 288) {
            const int rrow = u >> 4, side = (u >> 3) & 1, G = u & 7;
            int4 z = {0, 0, 0, 0};
            *(int4*)&img[(rrow * 34 + side * 33) * 128 + G * 16] = z;
        }
    }

    int aw[2];
    float offv[2], svf[2];
#pragma unroll
    for (int j = 0; j < 2; ++j) {
        const int c = cgrp * 32 + j * 16 + lane15;
        offv[j] = off[c];
        svf[j]  = scl[c];
        int a = (j * 16 + lane15) * 64 + q * 16;
        aw[j] = a ^ (((a >> 7) & 3) << 4);
    }

    for (int t = 0; t < 8; ++t) {
        const int tb = t * 32 + b;
        // stage rows y0-1 .. y0+16: 4608 units = 18 rows x 8 xg4 x 32 c4
#pragma unroll
        for (int k = 0; k < 18; ++k) {
            const int u = tid + k * 256;
            const int rrow = u >> 8, xg4 = (u >> 5) & 7, c4 = u & 31;
            const int y = y0 + rrow - 1;
            unsigned o0 = 0, o1 = 0, o2 = 0, o3 = 0;
            if (y >= 0 && y < 32) {
                const uint4 ld = *(const uint4*)(s2q +
                    (((size_t)tb * 256 + y * 8 + xg4) * 128 + c4 * 4) * 4);
                unsigned a, bp;
                a  = __builtin_amdgcn_perm(ld.y, ld.x, 0x0400u);
                bp = __builtin_amdgcn_perm(ld.w, ld.z, 0x0400u);
                o0 = __builtin_amdgcn_perm(bp, a, 0x05040100u);
                a  = __builtin_amdgcn_perm(ld.y, ld.x, 0x0501u);
                bp = __builtin_amdgcn_perm(ld.w, ld.z, 0x0501u);
                o1 = __builtin_amdgcn_perm(bp, a, 0x05040100u);
                a  = __builtin_amdgcn_perm(ld.y, ld.x, 0x0602u);
                bp = __builtin_amdgcn_perm(ld.w, ld.z, 0x0602u);
                o2 = __builtin_amdgcn_perm(bp, a, 0x05040100u);
                a  = __builtin_amdgcn_perm(ld.y, ld.x, 0x0703u);
                bp = __builtin_amdgcn_perm(ld.w, ld.z, 0x0703u);
                o3 = __builtin_amdgcn_perm(bp, a, 0x05040100u);
            }
            const int G = c4 >> 2, w4 = (c4 & 3) * 4;
            const int col = xg4 * 4 + 1;
            const int base = (rrow * 34 + col) * 128 + w4;
            *(unsigned*)&img[base +       ((G ^ ( col      & 7)) * 16)] = o0;
            *(unsigned*)&img[base + 128 + ((G ^ ((col + 1) & 7)) * 16)] = o1;
            *(unsigned*)&img[base + 256 + ((G ^ ((col + 2) & 7)) * 16)] = o2;
            *(unsigned*)&img[base + 384 + ((G ^ ((col + 3) & 7)) * 16)] = o3;
        }
        __syncthreads();   // weights (t=0) + img[t] ready

        i32x4 acc[8][2][2];   // [i][j][split]
#pragma unroll
        for (int i = 0; i < 8; ++i)
#pragma unroll
            for (int j = 0; j < 2; ++j)
#pragma unroll
                for (int s = 0; s < 2; ++s)
#pragma unroll
                    for (int rg = 0; rg < 4; ++rg) acc[i][j][s][rg] = 0;

#pragma unroll
        for (int tap = 0; tap < 9; ++tap) {
            const int dy = tap / 3 - 1;
            const int dx = tap - (tap / 3) * 3 - 1;
#pragma unroll
            for (int ci = 0; ci < 2; ++ci) {
                const int kc = tap * 2 + ci;
                i32x4 wb[2][2];
#pragma unroll
                for (int s = 0; s < 2; ++s)
#pragma unroll
                    for (int j = 0; j < 2; ++j)
                        wb[s][j] = *(const i32x4*)&wlds[(s * 18 + kc) * 2048 + aw[j]];
#pragma unroll
                for (int ih = 0; ih < 2; ++ih) {
                    i32x4 af[4];
#pragma unroll
                    for (int i4 = 0; i4 < 4; ++i4) {
                        const int i = ih * 4 + i4;
                        const int rowl = wv * 4 + (i >> 1) + 1 + dy;       // 0..17
                        const int col  = (i & 1) * 16 + lane15 + 1 + dx;   // 0..33
                        const int g    = (ci * 4 + q) ^ (col & 7);
                        af[i4] = *(const i32x4*)&img[(rowl * 34 + col) * 128 + g * 16];
                    }
#pragma unroll
                    for (int s = 0; s < 2; ++s)
#pragma unroll
                        for (int j = 0; j < 2; ++j)
#pragma unroll
                            for (int i4 = 0; i4 < 4; ++i4)
                                acc[ih * 4 + i4][j][s] = __builtin_amdgcn_mfma_i32_16x16x64_i8(
                                    af[i4], wb[s][j], acc[ih * 4 + i4][j][s], 0, 0, 0);
                }
            }
        }

        // epilogue: NCHW f32x4 stores (4 q-lanes per col = contiguous 64B)
#pragma unroll
        for (int i = 0; i < 8; ++i) {
            const int prow = (y0 + wv * 4 + (i >> 1)) * 32 + (i & 1) * 16 + q * 4;
#pragma unroll
            for (int j = 0; j < 2; ++j) {
                const int col = cgrp * 32 + j * 16 + lane15;
                f32x4 vv;
#pragma unroll
                for (int rg = 0; rg < 4; ++rg)
                    vv[rg] = fmaf((float)acc[i][j][0][rg]
                                + (float)acc[i][j][1][rg] * (1.0f / 254.0f),
                                svf[j], offv[j]);
                *(f32x4*)&out[(size_t)tb * 131072 + (size_t)col * 1024 + prow] = vv;
            }
        }
        if (t < 7) __syncthreads();   // all waves done reading img before restage
    }
}

extern "C" void kernel_launch(void* const* d_in, const int* in_sizes, int n_in,
                              void* d_out, int out_size, void* d_ws, size_t ws_size,
                              hipStream_t stream)
{
    const float* x  = (const float*)d_in[0];
    const float* w1 = (const float*)d_in[1];
    const float* g1 = (const float*)d_in[2];
    const float* b1 = (const float*)d_in[3];
    const float* m1 = (const float*)d_in[4];
    const float* v1 = (const float*)d_in[5];
    const float* w2 = (const float*)d_in[6];
    const float* g2 = (const float*)d_in[7];
    const float* b2 = (const float*)d_in[8];
    const float* m2 = (const float*)d_in[9];
    const float* v2 = (const float*)d_in[10];
    float* out = (float*)d_out;

    // ws layout: s1 i8 NHWC | s2 i8 quad-major | digits | off | scl | cnt | list | zb
    char* ws = (char*)d_ws;
    signed char* s1  = (signed char*)ws;                          //  33,554,432 B
    signed char* s2q = (signed char*)(ws + (size_t)33554432);     //  33,554,432 B
    signed char* wp  = (signed char*)(ws + (size_t)67108864);     //     737,280 B
    float*  off  = (float*)(ws + (size_t)67846144);               //       1,024 B
    float*  scl  = (float*)(ws + (size_t)67847168);               //       1,024 B
    int*    cnt  = (int*)  (ws + (size_t)67848192);               //           4 B
    int*    list = (int*)  (ws + (size_t)67848704);               //       16 MB cap
    signed char* zb = (signed char*)(ws + (size_t)84625920);      //       2,048 B

    prep_kernel<<<256, 128, 0, stream>>>(w1, g1, b1, m1, v1, w2, g2, b2, m2, v2,
                                         wp, off, scl, cnt, zb);
    if1_kernel<<<1024, 256, 0, stream>>>(x, s1);
    conv1_if2_kernel<<<512, 256, 0, stream>>>(s1, wp, off, scl, zb, s2q, cnt, list);
    redo_kernel<<<2048, 256, 0, stream>>>(s1, w1, g1, b1, m1, v1, cnt, list, s2q);
    conv2_kernel<<<256, 256, 0, stream>>>(s2q, wp + 442368, off + 128, scl + 128, out);
}